// Round 4
// baseline (93.180 us; speedup 1.0000x reference)
//
#include <hip/hip_runtime.h>

#define BLOCK 256
#define GRID 2048

__device__ __forceinline__ float fd_term(float a, float b) {
    // d = fb - a ; fb = (a<0 && b<0) ? b-a : a-b  =>  d = cond ? b-2a : -b
    float d = (a < 0.0f && b < 0.0f) ? fmaf(-2.0f, a, b) : b;
    return d * d; // squared, sign of d irrelevant
}

__global__ __launch_bounds__(BLOCK) void fd_partial(
    const float4* __restrict__ src4,
    const float4* __restrict__ tgt4,
    float* __restrict__ out,
    int n4, float invN)
{
    const int tid    = blockIdx.x * blockDim.x + threadIdx.x;
    const int stride = gridDim.x * blockDim.x;

    float acc = 0.0f;
    for (int i = tid; i < n4; i += stride) {
        const float4 b4 = src4[i];   // source
        const float4 a4 = tgt4[i];   // target
        acc += fd_term(a4.x, b4.x);
        acc += fd_term(a4.y, b4.y);
        acc += fd_term(a4.z, b4.z);
        acc += fd_term(a4.w, b4.w);
    }

    // wave-64 butterfly reduce
    #pragma unroll
    for (int off = 32; off; off >>= 1)
        acc += __shfl_down(acc, off, 64);

    __shared__ float lds[BLOCK / 64];
    const int lane = threadIdx.x & 63;
    const int wave = threadIdx.x >> 6;
    if (lane == 0) lds[wave] = acc;
    __syncthreads();

    if (threadIdx.x == 0) {
        // device-scope HW atomic (m20) — no hand-rolled cross-XCD fencing
        atomicAdd(out, (lds[0] + lds[1] + lds[2] + lds[3]) * invN);
    }
}

extern "C" void kernel_launch(void* const* d_in, const int* in_sizes, int n_in,
                              void* d_out, int out_size, void* d_ws, size_t ws_size,
                              hipStream_t stream)
{
    const float* src = (const float*)d_in[0];  // source -> b
    const float* tgt = (const float*)d_in[1];  // target -> a
    float* out = (float*)d_out;

    const long long n = (long long)in_sizes[0]; // 51,380,224 ; n % 4 == 0
    const int n4 = (int)(n >> 2);

    // graph-legal memset node: re-zeroes the accumulator every replay
    hipMemsetAsync(d_out, 0, sizeof(float), stream);
    fd_partial<<<GRID, BLOCK, 0, stream>>>(
        (const float4*)src, (const float4*)tgt, out, n4, 1.0f / (float)n);
}

// Round 5
// 75.010 us; speedup vs baseline: 1.2422x; 1.2422x over previous
//
#include <hip/hip_runtime.h>

#define BLOCK 256
#define GRID 2048

__device__ __forceinline__ float fd_term(float a, float b) {
    // d = fb - a ; fb = (a<0 && b<0) ? b-a : a-b  =>  d = cond ? b-2a : -b
    float d = (a < 0.0f && b < 0.0f) ? fmaf(-2.0f, a, b) : b;
    return d * d; // squared, sign of d irrelevant
}

__device__ __forceinline__ float fd_quad(float4 a4, float4 b4) {
    return fd_term(a4.x, b4.x) + fd_term(a4.y, b4.y)
         + fd_term(a4.z, b4.z) + fd_term(a4.w, b4.w);
}

__global__ __launch_bounds__(BLOCK) void fd_partial(
    const float4* __restrict__ src4,
    const float4* __restrict__ tgt4,
    float* __restrict__ partials,
    int n8)   // n/8: each thread handles 2 adjacent float4 per stream per iter
{
    const int tid    = blockIdx.x * blockDim.x + threadIdx.x;
    const int stride = gridDim.x * blockDim.x;

    float acc = 0.0f;
    #pragma unroll 1
    for (int i = tid; i < n8; i += stride) {
        const int base = 2 * i;           // wave reads 2KB contiguous per stream
        const float4 b0 = src4[base];
        const float4 b1 = src4[base + 1];
        const float4 a0 = tgt4[base];
        const float4 a1 = tgt4[base + 1];
        acc += fd_quad(a0, b0);
        acc += fd_quad(a1, b1);
    }

    // wave-64 butterfly reduce
    #pragma unroll
    for (int off = 32; off; off >>= 1)
        acc += __shfl_down(acc, off, 64);

    __shared__ float lds[BLOCK / 64];
    const int lane = threadIdx.x & 63;
    const int wave = threadIdx.x >> 6;
    if (lane == 0) lds[wave] = acc;
    __syncthreads();
    if (threadIdx.x == 0)
        partials[blockIdx.x] = lds[0] + lds[1] + lds[2] + lds[3];
}

__global__ __launch_bounds__(BLOCK) void fd_final(
    const float* __restrict__ partials,
    float* __restrict__ out,
    int nblocks, float invN)
{
    float acc = 0.0f;
    for (int i = threadIdx.x; i < nblocks; i += BLOCK)
        acc += partials[i];

    #pragma unroll
    for (int off = 32; off; off >>= 1)
        acc += __shfl_down(acc, off, 64);

    __shared__ float lds[BLOCK / 64];
    const int lane = threadIdx.x & 63;
    const int wave = threadIdx.x >> 6;
    if (lane == 0) lds[wave] = acc;
    __syncthreads();
    if (threadIdx.x == 0)
        out[0] = (lds[0] + lds[1] + lds[2] + lds[3]) * invN;
}

extern "C" void kernel_launch(void* const* d_in, const int* in_sizes, int n_in,
                              void* d_out, int out_size, void* d_ws, size_t ws_size,
                              hipStream_t stream)
{
    const float* src = (const float*)d_in[0];  // source -> b
    const float* tgt = (const float*)d_in[1];  // target -> a
    float* out      = (float*)d_out;
    float* partials = (float*)d_ws;            // GRID floats of scratch

    const long long n = (long long)in_sizes[0]; // 51,380,224 ; n % 8 == 0
    const int n8 = (int)(n >> 3);

    fd_partial<<<GRID, BLOCK, 0, stream>>>(
        (const float4*)src, (const float4*)tgt, partials, n8);
    fd_final<<<1, BLOCK, 0, stream>>>(partials, out, GRID, 1.0f / (float)n);
}